// Round 10
// baseline (298.343 us; speedup 1.0000x reference)
//
#include <hip/hip_runtime.h>

// Problem constants (from reference: shape (32,1,512,512) fp32)
#define BATCH 32
#define H 512
#define W 512
#define N_TOT (BATCH * H * W)          // 8388608
#define BAND 8                         // output rows per wave
#define NBLOCKS 1024                   // 4096 waves = 2048 bands x 2 halves
#define WS_FLOATS NBLOCKS

// R10: once-read sequential band walker, no barriers, compiler-counted
// waits. Fitted model over R0-R9: time ~ transactions x loaded-latency /
// (per-CU in-flight-line cap ~100 x 64B x 256CU). R5 (best, ~33us kernel)
// pays 3x vertical re-read transactions; R8's once-read LDS ring strangled
// pipeline depth with per-step vmcnt+barrier; R9 halved loads/px but also
// halved wave count -> ~40us. This corner: transactions ~1.06x unique AND
// zero barriers AND 2-deep register prefetch AND sequential row streams
// (DRAM row-buffer friendly, the copy kernel's 6.3 TB/s regime).
// Wave = half-row walker (4 px/lane, 256 px), BAND=8 rows downward.
// Per row per image: 1 float4 load (16 lines) + 1 uniform broadcast dword
// for the mid-column halo (1 line; R0 wasted 16-line dword loads on this).
// Column halos inside the wave via shfl; lane-edge = image edge (zero) or
// the broadcast value. 5-slot register ring, row k+3 issued while row k
// computes -> 2 rows always in flight per wave; the compiler's per-use
// s_waitcnt vmcnt(N) gives counted (never-zero) waits with NO barrier.
// 4096 waves at (256,4) = 4 waves/SIMD, the proven occupancy regime.
// Kept: XCD-bijective swizzle, per-block partial + 1-block finish.
// Harness dur_us includes ~83us of 268MB re-poison fills (not ours).

template <bool USE_PARTIALS>
__global__ __launch_bounds__(256, 4)
void fusion_loss_kernel(const float* __restrict__ A,
                        const float* __restrict__ B,
                        const float* __restrict__ F,
                        const int* __restrict__ scheme_arr,
                        float* __restrict__ sink)   // partials[] or out scalar
{
    __shared__ float red[4];

    const int t    = threadIdx.x;
    const int lane = t & 63;
    const int ty   = t >> 6;

    // XCD-bijective swizzle (1024 % 8 == 0): each XCD owns 128 consecutive
    // logical blocks -> band-boundary re-reads are same-XCD L2 hits.
    const int bid = blockIdx.x;
    const int lb  = (bid & 7) * (NBLOCKS / 8) + (bid >> 3);

    const int w    = lb * 4 + ty;        // wave id 0..4095
    const int half = w & 1;              // 0: cols 0-255, 1: cols 256-511
    const int band = w >> 1;             // 0..2047
    const int b    = band >> 6;          // batch (64 bands per image)
    const int r0   = (band & 63) << 3;   // first output row (mult of 8)
    const int base = b * (H * W);
    const int scheme = scheme_arr[b];
    const int colbase = (half << 8) + (lane << 2);   // this lane's 4 px
    const int hcol = half ? 255 : 256;   // mid-column halo this half needs

    // 5-slot register ring: rc = 4 px, hv = the uniform mid-column halo px
    float4 rc[3][5];
    float  hv[3][5];

    // load input row r0+j into slot s (wave-uniform validity; OOB row ->
    // zeros = reference 'same' conv zero padding)
#define LOADR(j_, s_) do {                                                  \
    const int y_ = r0 + (j_);                                               \
    if ((unsigned)y_ < (unsigned)H) {   /* wave-uniform */                  \
        const int ro_ = base + y_ * W;                                      \
        rc[0][s_] = *reinterpret_cast<const float4*>(A + ro_ + colbase);    \
        rc[1][s_] = *reinterpret_cast<const float4*>(B + ro_ + colbase);    \
        rc[2][s_] = *reinterpret_cast<const float4*>(F + ro_ + colbase);    \
        hv[0][s_] = A[ro_ + hcol];      /* uniform addr -> 1 line */        \
        hv[1][s_] = B[ro_ + hcol];                                          \
        hv[2][s_] = F[ro_ + hcol];                                          \
    } else {                                                                \
        const float4 z_ = make_float4(0.f, 0.f, 0.f, 0.f);                  \
        rc[0][s_] = z_; rc[1][s_] = z_; rc[2][s_] = z_;                     \
        hv[0][s_] = 0.f; hv[1][s_] = 0.f; hv[2][s_] = 0.f;                  \
    }                                                                       \
} while (0)

    // 6-wide window (cols x0-1..x0+4) from one slot's float4 + halo.
    // lane 0 left edge: image edge (half 0 -> 0) or broadcast col 255;
    // lane 63 right edge: broadcast col 256 (half 0) or image edge (0).
#define WIN(w_, f4_, h_) do {                                               \
    float l_ = __shfl_up((f4_).w, 1, 64);                                   \
    float r_ = __shfl_down((f4_).x, 1, 64);                                 \
    if (lane == 0)  l_ = half ? (h_) : 0.f;                                 \
    if (lane == 63) r_ = half ? 0.f : (h_);                                 \
    w_[0] = l_;                                                             \
    w_[1] = (f4_).x; w_[2] = (f4_).y; w_[3] = (f4_).z; w_[4] = (f4_).w;     \
    w_[5] = r_;                                                             \
} while (0)

    float acc = 0.f;

    // one output row from ring slots sm_(y-1), sc_(y), sp_(y+1):
    // separable sobel (s = m+2c+p col sums, d = m-p; gx = s[j+2]-s[j],
    // gy = d[j]+2d[j+1]+d[j+2]; verified exact, absmax 0 in R7/R9) + l_loss
#define STEPC(sm_, sc_, sp_) do {                                           \
    float sob4[4];                                                          \
    _Pragma("unroll")                                                       \
    for (int im_ = 0; im_ < 3; ++im_) {                                     \
        float wm6[6], wc6[6], wp6[6];                                       \
        WIN(wm6, rc[im_][sm_], hv[im_][sm_]);                               \
        WIN(wc6, rc[im_][sc_], hv[im_][sc_]);                               \
        WIN(wp6, rc[im_][sp_], hv[im_][sp_]);                               \
        float s_[6], d_[6];                                                 \
        _Pragma("unroll")                                                   \
        for (int j_ = 0; j_ < 6; ++j_) {                                    \
            s_[j_] = wm6[j_] + 2.f * wc6[j_] + wp6[j_];                     \
            d_[j_] = wm6[j_] - wp6[j_];                                     \
        }                                                                   \
        _Pragma("unroll")                                                   \
        for (int j_ = 0; j_ < 4; ++j_) {                                    \
            const float o_ = fabsf(s_[j_ + 2] - s_[j_])                     \
                           + fabsf(d_[j_] + 2.f * d_[j_ + 1] + d_[j_ + 2]); \
            if (im_ == 0)      sob4[j_] = o_;                               \
            else if (im_ == 1) sob4[j_] = fmaxf(sob4[j_], o_);              \
            else               acc += fabsf(o_ - sob4[j_]);                 \
        }                                                                   \
    }                                                                       \
    {   const float4 a4_ = rc[0][sc_], b4_ = rc[1][sc_], f4_ = rc[2][sc_];  \
        const float av_[4] = {a4_.x, a4_.y, a4_.z, a4_.w};                  \
        const float bv_[4] = {b4_.x, b4_.y, b4_.z, b4_.w};                  \
        const float fv_[4] = {f4_.x, f4_.y, f4_.z, f4_.w};                  \
        _Pragma("unroll")                                                   \
        for (int j_ = 0; j_ < 4; ++j_) {                                    \
            const float ab_ = (scheme == 0) ? 0.5f * (av_[j_] + bv_[j_])    \
                            : (scheme == 1) ? fmaxf(av_[j_], bv_[j_])       \
                            : 0.f;                                          \
            acc += fabsf(ab_ - fv_[j_]);                                    \
        }                                                                   \
    }                                                                       \
} while (0)

    // prologue: rows r0-1..r0+2 into slots 4,0,1,2 (4 rows in flight)
    LOADR(-1, 4); LOADR(0, 0); LOADR(1, 1); LOADR(2, 2);

    // step k: issue row k+3 (slot (k+3)%5, whose old row k-2 was last read
    // at step k-1), then compute row k from slots (k+4)%5, k%5, (k+1)%5.
    // Row k+1 was issued at step k-2 -> ~2 compute-phases of latency slack;
    // rows k+2, k+3 stay in flight across the compiler's counted vmcnt.
#pragma unroll
    for (int k = 0; k < BAND; ++k) {
        if (k < BAND - 2) LOADR(k + 3, (k + 3) % 5);
        STEPC((k + 4) % 5, k % 5, (k + 1) % 5);
    }

#undef LOADR
#undef WIN
#undef STEPC

    // ---- reduction: 64-lane shuffle, cross-wave via LDS, one plain store
    // per block to a distinct workspace slot (parallel drain, no atomics).
#pragma unroll
    for (int offp = 32; offp > 0; offp >>= 1)
        acc += __shfl_down(acc, offp, 64);
    if (lane == 0) red[ty] = acc;
    __syncthreads();
    if (t == 0) {
        const float s = red[0] + red[1] + red[2] + red[3];
        if (USE_PARTIALS)
            sink[bid] = s;
        else
            atomicAdd(sink, s * (1.0f / (float)N_TOT)); // fallback path
    }
}

// 1-block finish: sum NBLOCKS=1024 partials (256 threads x 1 float4),
// scale by 1/N, write the scalar. Kernel boundary on the stream guarantees
// visibility of kernel1's plain stores.
__global__ __launch_bounds__(256)
void fusion_finish(const float* __restrict__ partials, float* __restrict__ out)
{
    __shared__ float red[4];
    const int t    = threadIdx.x;
    const int lane = t & 63;
    const int ty   = t >> 6;

    const float4 p = reinterpret_cast<const float4*>(partials)[t];
    float v = (p.x + p.y) + (p.z + p.w);
#pragma unroll
    for (int off = 32; off > 0; off >>= 1)
        v += __shfl_down(v, off, 64);
    if (lane == 0) red[ty] = v;
    __syncthreads();
    if (t == 0)
        out[0] = (red[0] + red[1] + red[2] + red[3]) * (1.0f / (float)N_TOT);
}

extern "C" void kernel_launch(void* const* d_in, const int* in_sizes, int n_in,
                              void* d_out, int out_size, void* d_ws, size_t ws_size,
                              hipStream_t stream)
{
    const float* A = (const float*)d_in[0];
    const float* B = (const float*)d_in[1];
    const float* F = (const float*)d_in[2];
    const int* scheme = (const int*)d_in[3];
    float* out = (float*)d_out;

    if (d_ws != nullptr && ws_size >= WS_FLOATS * sizeof(float)) {
        float* partials = (float*)d_ws;   // 4 KB, 16B-aligned
        fusion_loss_kernel<true><<<dim3(NBLOCKS), dim3(256), 0, stream>>>(
            A, B, F, scheme, partials);
        fusion_finish<<<dim3(1), dim3(256), 0, stream>>>(partials, out);
    } else {
        // Fallback: atomic path (d_out poisoned -> zero it).
        hipMemsetAsync(out, 0, sizeof(float), stream);
        fusion_loss_kernel<false><<<dim3(NBLOCKS), dim3(256), 0, stream>>>(
            A, B, F, scheme, out);
    }
}

// Round 11
// 121.158 us; speedup vs baseline: 2.4624x; 2.4624x over previous
//
#include <hip/hip_runtime.h>

// Problem constants (from reference: shape (32,1,512,512) fp32)
#define BATCH 32
#define H 512
#define W 512
#define N_TOT (BATCH * H * W)          // 8388608
#define ROWS_TOTAL (BATCH * H)         // 16384
#define NBLOCKS (ROWS_TOTAL / 4)       // 4096 blocks x 4 waves = 1 row/wave
#define WS_FLOATS NBLOCKS

// R11 = R5 verbatim (the session's verified best: 121.7 us E2E, kernel
// ~33 us), locked in after R6-R10 all regressed. Final model: the kernel
// is bound by per-CU in-flight-miss capacity x loaded HBM latency
// (~3-3.5 TB/s effective for any stencil-shaped reader on this chip);
// the ~10-16 us pure-streaming floor requires deep-pipeline structures
// (LDS rings with counted vmcnt, register rings with modular slots) that
// this toolchain's allocator reliably breaks: R3/R6/R10 all spilled
// (24/176/240 MB scratch), R4/R8's barrier-vmcnt chains serialized
// (58/44 us), phased TLP variants (R7/R9) lost load-hoisting depth (~40).
// R5's recipe: wave = one full 512-px row, 8 px/lane; ALL 18 float4 loads
// issued up front (18 KB in flight/wave, max MLP the allocator tolerates
// at VGPR=128 / 4 waves/SIMD); column halos via __shfl (lane edges ==
// image edges == zero pad -> no halo loads, no cross-wave traffic); zero
// __syncthreads in the hot path; XCD-bijective block swizzle; per-block
// partial store + 1-block finish (no atomics; R1 showed the cross-XCD
// same-address atomicAdd drain). Harness dur_us includes ~83 us of 268 MB
// fillBufferAligned re-poison dispatches (harness-owned, they also flush
// L3 so inputs are cold every iteration) -- not optimizable from here.

template <bool USE_PARTIALS>
__global__ __launch_bounds__(256, 4)
void fusion_loss_kernel(const float* __restrict__ A,
                        const float* __restrict__ B,
                        const float* __restrict__ F,
                        const int* __restrict__ scheme_arr,
                        float* __restrict__ sink)   // partials[] or out scalar
{
    __shared__ float red[4];

    const int t    = threadIdx.x;
    const int lane = t & 63;
    const int ty   = t >> 6;

    // XCD-bijective swizzle: hw assigns xcd ~ blockIdx%8; remap so each XCD
    // owns NBLOCKS/8 = 512 consecutive logical blocks (2048 contiguous rows).
    const int bid = blockIdx.x;
    const int lb  = (bid & 7) * (NBLOCKS / 8) + (bid >> 3);

    const int gy  = (lb << 2) | ty;       // global row 0..16383 (1 row/wave)
    const int b   = gy >> 9;              // batch (rows 512-aligned, blocks
    const int y   = gy & (H - 1);         //  4-row aligned -> no batch split)
    const int x0  = lane << 3;            // 8 px per lane
    const int scheme = scheme_arr[b];

    const int off = gy * W + x0;          // gy*W == (b*H + y)*W
    const bool vm = (y > 0);
    const bool vp = (y < H - 1);

    // u0 = cols x0..x0+3, u1 = cols x0+4..x0+7; rows r: 0=y-1, 1=y, 2=y+1
    float4 u0[3][3], u1[3][3];
    {
        const float* ptr[3] = {A + off, B + off, F + off};
#pragma unroll
        for (int im = 0; im < 3; ++im) {
            const float* p = ptr[im];
            u0[im][1] = *reinterpret_cast<const float4*>(p);
            u1[im][1] = *reinterpret_cast<const float4*>(p + 4);
            if (vm) {   // wave-uniform branch
                u0[im][0] = *reinterpret_cast<const float4*>(p - W);
                u1[im][0] = *reinterpret_cast<const float4*>(p - W + 4);
            } else {    // reference 'same' conv zero padding
                u0[im][0] = make_float4(0.f, 0.f, 0.f, 0.f);
                u1[im][0] = make_float4(0.f, 0.f, 0.f, 0.f);
            }
            if (vp) {
                u0[im][2] = *reinterpret_cast<const float4*>(p + W);
                u1[im][2] = *reinterpret_cast<const float4*>(p + W + 4);
            } else {
                u0[im][2] = make_float4(0.f, 0.f, 0.f, 0.f);
                u1[im][2] = make_float4(0.f, 0.f, 0.f, 0.f);
            }
        }
    }

    float acc = 0.f;

    // ---- l_loss on this row's 8 px (center rows of A,B,F) ----
#pragma unroll
    for (int hh = 0; hh < 2; ++hh) {
        const float4 a4 = hh ? u1[0][1] : u0[0][1];
        const float4 b4 = hh ? u1[1][1] : u0[1][1];
        const float4 f4 = hh ? u1[2][1] : u0[2][1];
        const float av[4] = {a4.x, a4.y, a4.z, a4.w};
        const float bv[4] = {b4.x, b4.y, b4.z, b4.w};
        const float fv[4] = {f4.x, f4.y, f4.z, f4.w};
#pragma unroll
        for (int j = 0; j < 4; ++j) {
            const float ab = (scheme == 0) ? 0.5f * (av[j] + bv[j])
                           : (scheme == 1) ? fmaxf(av[j], bv[j])
                           : 0.f;
            acc += fabsf(ab - fv[j]);
        }
    }

    // ---- sobel: per image, 10-wide windows for 3 rows, 8 outputs ----
    float sobM[8];
#pragma unroll
    for (int im = 0; im < 3; ++im) {
        float v[3][10];
#pragma unroll
        for (int r = 0; r < 3; ++r) {
            const float4 a = u0[im][r];
            const float4 c = u1[im][r];
            // col x0-1 = lane-1's c.w; col x0+8 = lane+1's a.x.
            // Lane 0 / lane 63 edges are image edges -> zero pad.
            float lN = __shfl_up(c.w, 1, 64);
            float rN = __shfl_down(a.x, 1, 64);
            if (lane == 0)  lN = 0.f;
            if (lane == 63) rN = 0.f;
            v[r][0] = lN;
            v[r][1] = a.x; v[r][2] = a.y; v[r][3] = a.z; v[r][4] = a.w;
            v[r][5] = c.x; v[r][6] = c.y; v[r][7] = c.z; v[r][8] = c.w;
            v[r][9] = rN;
        }
#pragma unroll
        for (int j = 0; j < 8; ++j) {
            const float gx = (v[0][j + 2] - v[0][j])
                           + 2.f * (v[1][j + 2] - v[1][j])
                           + (v[2][j + 2] - v[2][j]);
            const float gyv = (v[0][j] + 2.f * v[0][j + 1] + v[0][j + 2])
                            - (v[2][j] + 2.f * v[2][j + 1] + v[2][j + 2]);
            const float sob = fabsf(gx) + fabsf(gyv);
            if (im == 0)      sobM[j] = sob;
            else if (im == 1) sobM[j] = fmaxf(sobM[j], sob);
            else              acc += fabsf(sob - sobM[j]);
        }
    }

    // ---- reduction: 64-lane shuffle, cross-wave via LDS, one plain store
    // per block to a distinct workspace slot (parallel drain, no atomics).
#pragma unroll
    for (int offp = 32; offp > 0; offp >>= 1)
        acc += __shfl_down(acc, offp, 64);
    if (lane == 0) red[ty] = acc;
    __syncthreads();
    if (t == 0) {
        const float s = red[0] + red[1] + red[2] + red[3];
        if (USE_PARTIALS)
            sink[bid] = s;
        else
            atomicAdd(sink, s * (1.0f / (float)N_TOT)); // fallback path
    }
}

// 1-block finish: sum NBLOCKS=4096 partials (256 threads x 4 float4),
// scale by 1/N, write the scalar. Kernel boundary on the stream guarantees
// visibility of kernel1's plain stores.
__global__ __launch_bounds__(256)
void fusion_finish(const float* __restrict__ partials, float* __restrict__ out)
{
    __shared__ float red[4];
    const int t    = threadIdx.x;
    const int lane = t & 63;
    const int ty   = t >> 6;

    float s = 0.f;
#pragma unroll
    for (int k = 0; k < 4; ++k) {
        const float4 p = reinterpret_cast<const float4*>(partials)[t + 256 * k];
        s += (p.x + p.y) + (p.z + p.w);
    }
#pragma unroll
    for (int off = 32; off > 0; off >>= 1)
        s += __shfl_down(s, off, 64);
    if (lane == 0) red[ty] = s;
    __syncthreads();
    if (t == 0)
        out[0] = (red[0] + red[1] + red[2] + red[3]) * (1.0f / (float)N_TOT);
}

extern "C" void kernel_launch(void* const* d_in, const int* in_sizes, int n_in,
                              void* d_out, int out_size, void* d_ws, size_t ws_size,
                              hipStream_t stream)
{
    const float* A = (const float*)d_in[0];
    const float* B = (const float*)d_in[1];
    const float* F = (const float*)d_in[2];
    const int* scheme = (const int*)d_in[3];
    float* out = (float*)d_out;

    if (d_ws != nullptr && ws_size >= WS_FLOATS * sizeof(float)) {
        float* partials = (float*)d_ws;   // 16 KB, 16B-aligned
        fusion_loss_kernel<true><<<dim3(NBLOCKS), dim3(256), 0, stream>>>(
            A, B, F, scheme, partials);
        fusion_finish<<<dim3(1), dim3(256), 0, stream>>>(partials, out);
    } else {
        // Fallback: atomic path (d_out poisoned -> zero it).
        hipMemsetAsync(out, 0, sizeof(float), stream);
        fusion_loss_kernel<false><<<dim3(NBLOCKS), dim3(256), 0, stream>>>(
            A, B, F, scheme, out);
    }
}